// Round 13
// baseline (113.599 us; speedup 1.0000x reference)
//
#include <hip/hip_runtime.h>

typedef short bf16x8 __attribute__((ext_vector_type(8)));
typedef float f32x4 __attribute__((ext_vector_type(4)));
typedef unsigned short u16;
typedef unsigned short u16x8 __attribute__((ext_vector_type(8)));
typedef unsigned short u16x4 __attribute__((ext_vector_type(4), may_alias));
typedef float f32x4_a __attribute__((ext_vector_type(4), may_alias));

__device__ __forceinline__ u16 f2bf(float f) {
    union { float f; unsigned u; } v; v.f = f;
    unsigned r = v.u + 0x7fffu + ((v.u >> 16) & 1u);
    return (u16)(r >> 16);
}
// cheap round-half-up (for P: normalization cancels the tiny bias)
__device__ __forceinline__ u16 f2bf_rhu(float f) {
    union { float f; unsigned u; } v; v.f = f;
    return (u16)((v.u + 0x8000u) >> 16);
}

// async global->LDS, 16B per lane. lds base must be wave-uniform (HW adds lane*16).
__device__ __forceinline__ void gld_lds16(const void* g, void* l) {
    __builtin_amdgcn_global_load_lds(
        (const __attribute__((address_space(1))) void*)g,
        (__attribute__((address_space(3))) void*)l, 16, 0, 0);
}

// ---------------------------------------------------------------------------
// Fused prep: x fp32->bf16 (blocks 0..2047), w_qkv transpose+cvt (2048..5119),
// w_proj transpose+cvt (5120..6143).
// ---------------------------------------------------------------------------
__global__ __launch_bounds__(256) void prep_kernel(
    const float* __restrict__ x, u16* __restrict__ xb,
    const float* __restrict__ w_qkv, u16* __restrict__ wqkvT,
    const float* __restrict__ w_proj, u16* __restrict__ wprojT) {
    __shared__ float tile[32][33];
    const int b = blockIdx.x, tid = threadIdx.x;
    if (b < 2048) {
        const int i = b * 256 + tid;
        float4 a = ((const float4*)x)[i * 2];
        float4 c = ((const float4*)x)[i * 2 + 1];
        u16x8 h;
        h[0] = f2bf(a.x); h[1] = f2bf(a.y); h[2] = f2bf(a.z); h[3] = f2bf(a.w);
        h[4] = f2bf(c.x); h[5] = f2bf(c.y); h[6] = f2bf(c.z); h[7] = f2bf(c.w);
        *(u16x8*)(xb + (size_t)i * 8) = h;
        return;
    }
    const float* in; u16* out; int N, bx;
    if (b < 5120) { bx = b - 2048; in = w_qkv; out = wqkvT; N = 3072; }
    else          { bx = b - 5120; in = w_proj; out = wprojT; N = 1024; }
    const int nblk = N / 32;
    const int n0 = (bx % nblk) * 32, k0 = (bx / nblk) * 32;
    const int tx = tid & 31, ty = tid >> 5;
#pragma unroll
    for (int i = 0; i < 32; i += 8)
        tile[ty + i][tx] = in[(size_t)(k0 + ty + i) * N + n0 + tx];
    __syncthreads();
#pragma unroll
    for (int i = 0; i < 32; i += 8)
        out[(size_t)(n0 + ty + i) * 1024 + k0 + tx] = f2bf(tile[tx][ty + i]);
}

// ---------------------------------------------------------------------------
// GEMM: C[M,N] = A[M,K](bf16) * Bt[N,K]^T + bias
// BM=128, BN in {128,64}. 4 waves (2x2), BK=64, global_load_lds x16 staging
// with both-sides XOR swizzle (frag reads 2-way = free), 16 K-steps.
// OUTMODE 0: scatter Q (pre-scaled by 0.125*log2e) / K as [B,H,T,D],
//            V transposed as [B,H,D,T].  OUTMODE 1: fp32 C + bias.
// ---------------------------------------------------------------------------
#define QSCALE 0.180336880f  // 0.125 * log2(e)

template <int OUTMODE, int BN>
__global__ __launch_bounds__(256) void gemm_m97(
    const u16* __restrict__ A, const u16* __restrict__ Bt,
    const float* __restrict__ bias, float* __restrict__ Cf,
    u16* __restrict__ Qo, u16* __restrict__ Ko, u16* __restrict__ Vt,
    int M, int N, int K) {
    constexpr int NF = BN / 32;  // n-frags per wave (wave covers BN/2 cols)
    __shared__ __align__(16) u16 lA[128 * 64];
    __shared__ __align__(16) u16 lB[BN * 64];

    const int tid = threadIdx.x;
    const int lane = tid & 63, wid = tid >> 6;
    const int wr = wid >> 1, wc = wid & 1;
    const int fr = lane & 15, fq = lane >> 4;
    const int m0 = blockIdx.y * 128, n0 = blockIdx.x * BN;

    const int gsrc = (lane & 7) ^ (lane >> 3);
    const u16* gA0 = A + (size_t)(m0 + (tid >> 3)) * K + gsrc * 8;
    const u16* gB0 = Bt + (size_t)(n0 + (tid >> 3)) * K + gsrc * 8;
    u16* lAw = lA + wid * 512;
    u16* lBw = lB + wid * 512;

    const int r7 = fr & 7;
    const int gk[2] = { ((0 + fq) ^ r7) * 8, ((4 + fq) ^ r7) * 8 };

    f32x4 acc[4][NF];
#pragma unroll
    for (int m = 0; m < 4; m++)
#pragma unroll
        for (int n = 0; n < NF; n++)
#pragma unroll
            for (int r = 0; r < 4; r++) acc[m][n][r] = 0.f;

    for (int k0 = 0; k0 < K; k0 += 64) {
        __syncthreads();
#pragma unroll
        for (int c = 0; c < 4; c++)
            gld_lds16(gA0 + (size_t)(c * 32) * K + k0, lAw + c * 2048);
#pragma unroll
        for (int c = 0; c < BN / 32; c++)
            gld_lds16(gB0 + (size_t)(c * 32) * K + k0, lBw + c * 2048);
        __syncthreads();

#pragma unroll
        for (int kf = 0; kf < 2; kf++) {
            bf16x8 a[4], b[NF];
#pragma unroll
            for (int m = 0; m < 4; m++)
                a[m] = *(const bf16x8*)&lA[(wr * 64 + m * 16 + fr) * 64 + gk[kf]];
#pragma unroll
            for (int n = 0; n < NF; n++)
                b[n] = *(const bf16x8*)&lB[(wc * (BN / 2) + n * 16 + fr) * 64 + gk[kf]];
#pragma unroll
            for (int m = 0; m < 4; m++)
#pragma unroll
                for (int n = 0; n < NF; n++)
                    acc[m][n] = __builtin_amdgcn_mfma_f32_16x16x32_bf16(a[m], b[n], acc[m][n], 0, 0, 0);
        }
    }

#pragma unroll
    for (int m = 0; m < 4; m++) {
#pragma unroll
        for (int n = 0; n < NF; n++) {
            const int row0 = m0 + wr * 64 + m * 16 + fq * 4;
            const int col = n0 + wc * (BN / 2) + n * 16 + fr;
            float v4[4];
#pragma unroll
            for (int r = 0; r < 4; r++) v4[r] = acc[m][n][r] + bias[col];
            if (OUTMODE == 0) {
                const int bb = row0 >> 11, t0 = row0 & 2047;
                const int sec = col >> 10, cc = col & 1023;
                const int h = cc >> 6, d = cc & 63;
                if (sec == 0) {
#pragma unroll
                    for (int r = 0; r < 4; r++)
                        Qo[(((size_t)(bb * 16 + h) * 2048 + t0 + r) << 6) + d] = f2bf(v4[r] * QSCALE);
                } else if (sec == 1) {
#pragma unroll
                    for (int r = 0; r < 4; r++)
                        Ko[(((size_t)(bb * 16 + h) * 2048 + t0 + r) << 6) + d] = f2bf(v4[r]);
                } else {
                    ushort4 p;
                    p.x = f2bf(v4[0]); p.y = f2bf(v4[1]); p.z = f2bf(v4[2]); p.w = f2bf(v4[3]);
                    *(ushort4*)&Vt[(((size_t)(bb * 16 + h) * 64 + d) << 11) + t0] = p;
                }
            } else {
#pragma unroll
                for (int r = 0; r < 4; r++)
                    Cf[(size_t)(row0 + r) * N + col] = v4[r];
            }
        }
    }
}

// ---------------------------------------------------------------------------
// Causal flash attention, swapped-operand + 2x2 wave role split +
// V DIRECT-TO-REGISTER from global (V^T is L2-resident: head pinned to one
// XCD, 1 MB of K+V per 4 heads). Kills the lV stage+read (24 KB/block-tile
// of LDS traffic, -37%) and halves staging to 2 gld_lds per tile.
// Single barrier per tile: each wave's end-of-iter vmcnt(0) covers its own
// K-DMA; the barrier then publishes all waves' staging. Safe because a wave
// can only enter iter kt+1 (and overwrite lK[cur^1]) after ALL waves passed
// the kt barrier, i.e. finished reading lK[cur].
// Q,K bf16 [BH,T,64]; Vt bf16 [BH,64,T]; O bf16 [B,T,H*64].
// Block: 4 waves, 64 q-rows; grid 1024, heavy q-tiles first.
// ---------------------------------------------------------------------------
__global__ __launch_bounds__(256, 4) void attn_kernel(const u16* __restrict__ Q,
                                                      const u16* __restrict__ Kg,
                                                      const u16* __restrict__ Vt,
                                                      u16* __restrict__ O) {
    // unified smem: lK dbuf (2x8 KB) + lP (4x2 KB) = 24 KB; the f32 combine
    // scratch (20 KB) overlays the whole block after the loop (all dead).
    __shared__ __align__(16) u16 smem[12288];
    u16* lK0 = smem;                 // [64*64], swizzled
    u16* lK1 = smem + 4096;
    u16* lPw;                        // this wave's P slab [32*32]

    const int tid = threadIdx.x;
    const int lane = tid & 63, wid = tid >> 6;
    const int fr = lane & 15, fq = lane >> 4;
    const int kw = wid >> 1, qw = wid & 1;  // k-half / q-half roles
    lPw = smem + 8192 + wid * 1024;
    const int bh = blockIdx.x & 31;
    const int qi = 31 - (blockIdx.x >> 5);  // heavy blocks first
    const int qb0 = qi * 64;
    const size_t base = (size_t)bh * (2048 * 64);
    const u16* Qp = Q + base;
    const u16* Kp = Kg + base;
    const u16* Vp = Vt + base;  // [64][2048]

    const int q0w = qb0 + qw * 32;
    bf16x8 qa[2][2];  // [qg][kf]
#pragma unroll
    for (int qg = 0; qg < 2; qg++)
#pragma unroll
        for (int kf = 0; kf < 2; kf++)
            qa[qg][kf] = *(const bf16x8*)&Qp[(size_t)(q0w + qg * 16 + fr) * 64 + kf * 32 + fq * 8];
    asm volatile("s_waitcnt vmcnt(0)" ::: "memory");

    bf16x8 vones;
#pragma unroll
    for (int j = 0; j < 8; j++) vones[j] = (short)0x3F80;  // bf16 1.0

    f32x4 o[4][2], lsum[2];  // [dg][qg] / [qg]
#pragma unroll
    for (int qg = 0; qg < 2; qg++) {
#pragma unroll
        for (int r = 0; r < 4; r++) lsum[qg][r] = 0.f;
#pragma unroll
        for (int dg = 0; dg < 4; dg++)
#pragma unroll
            for (int r = 0; r < 4; r++) o[dg][qg][r] = 0.f;
    }

    // --- K staging geometry (both-sides swizzle, rule #21) ---
    const int srow0 = wid * 8 + (lane >> 3);
    const int gsrc = (lane & 7) ^ (lane >> 3);
    const u16* kSrc0 = Kp + (size_t)srow0 * 64 + gsrc * 8;

    // --- fragment read granules (same XOR on read) ---
    const int r7 = fr & 7;
    const int gk0 = ((0 + fq) ^ r7) * 8;        // K d-granule, kf=0
    const int gk1 = ((4 + fq) ^ r7) * 8;        // K d-granule, kf=1

    // --- V global base: lane reads V^T[d=dg*16+fr][kt0 + kw*32 + fq*8 ..+8]
    const u16* vBase = Vp + (size_t)fr * 2048 + kw * 32 + fq * 8;

    const int nt = qi + 1;

#define STAGE_K(bufp, kt0_)                                                     \
    do {                                                                        \
        u16* _lkw = (bufp) + wid * 512;                                         \
        gld_lds16(kSrc0 + (size_t)(kt0_) * 64, _lkw);                           \
        gld_lds16(kSrc0 + (size_t)((kt0_) + 32) * 64, _lkw + 2048);             \
    } while (0)

    STAGE_K(lK0, 0);
    asm volatile("s_waitcnt vmcnt(0)" ::: "memory");
    __builtin_amdgcn_s_barrier();

    for (int kt = 0; kt < nt; kt++) {
        const int kt0 = kt << 6;
        const u16* lKc = (kt & 1) ? lK1 : lK0;
        u16* lKn = (kt & 1) ? lK0 : lK1;

        // V for THIS tile: issue first (compiler inserts the exact vmcnt
        // before the PV reads of va; gld_lds below are newer ops).
        bf16x8 va[4];
#pragma unroll
        for (int dg = 0; dg < 4; dg++)
            va[dg] = *(const bf16x8*)(vBase + (size_t)dg * 32768 + kt0);

        if (kt + 1 < nt) STAGE_K(lKn, kt0 + 64);

        // S^T[k32][q32] = K_half Q_half^T   (exp2 domain; Q pre-scaled)
        f32x4 s[2][2];  // [kg][qg]
#pragma unroll
        for (int kg = 0; kg < 2; kg++)
#pragma unroll
            for (int qg = 0; qg < 2; qg++)
#pragma unroll
                for (int r = 0; r < 4; r++) s[kg][qg][r] = 0.f;
        __builtin_amdgcn_s_setprio(1);
#pragma unroll
        for (int kg = 0; kg < 2; kg++) {
            const int krow = (kw * 32 + kg * 16 + fr) * 64;
            bf16x8 kb0 = *(const bf16x8*)&lKc[krow + gk0];
            bf16x8 kb1 = *(const bf16x8*)&lKc[krow + gk1];
#pragma unroll
            for (int qg = 0; qg < 2; qg++) {
                s[kg][qg] = __builtin_amdgcn_mfma_f32_16x16x32_bf16(kb0, qa[qg][0], s[kg][qg], 0, 0, 0);
                s[kg][qg] = __builtin_amdgcn_mfma_f32_16x16x32_bf16(kb1, qa[qg][1], s[kg][qg], 0, 0, 0);
            }
        }
        __builtin_amdgcn_s_setprio(0);

        if (kt == nt - 1) {  // only the diagonal tile can cross the boundary
#pragma unroll
            for (int kg = 0; kg < 2; kg++) {
                const int kg0 = kt0 + kw * 32 + kg * 16 + fq * 4;
#pragma unroll
                for (int qg = 0; qg < 2; qg++) {
                    const int qg0 = q0w + qg * 16 + fr;
#pragma unroll
                    for (int r = 0; r < 4; r++)
                        if (kg0 + r > qg0) s[kg][qg][r] = -200.f;  // exp2 -> 0
                }
            }
        }

        // P = exp2(S) -> lP[q32][k32]: b64 at row q, granule (kg*2+(fq>>1))^(q&3)
#pragma unroll
        for (int kg = 0; kg < 2; kg++)
#pragma unroll
            for (int qg = 0; qg < 2; qg++) {
                const int ql = qg * 16 + fr;
                u16x4 w;
                w[0] = f2bf_rhu(__builtin_amdgcn_exp2f(s[kg][qg][0]));
                w[1] = f2bf_rhu(__builtin_amdgcn_exp2f(s[kg][qg][1]));
                w[2] = f2bf_rhu(__builtin_amdgcn_exp2f(s[kg][qg][2]));
                w[3] = f2bf_rhu(__builtin_amdgcn_exp2f(s[kg][qg][3]));
                const int g = (kg * 2 + (fq >> 1)) ^ (ql & 3);
                *(u16x4*)&lPw[ql * 32 + g * 8 + (fq & 1) * 4] = w;
            }
        asm volatile("" ::: "memory");  // order lP writes before lP reads

        // O^T += V^T_half P ; l += 1*P   (va waited automatically)
        __builtin_amdgcn_s_setprio(1);
#pragma unroll
        for (int qg = 0; qg < 2; qg++) {
            const int ql = qg * 16 + fr;
            bf16x8 pb = *(const bf16x8*)&lPw[ql * 32 + (fq ^ (ql & 3)) * 8];
            lsum[qg] = __builtin_amdgcn_mfma_f32_16x16x32_bf16(vones, pb, lsum[qg], 0, 0, 0);
#pragma unroll
            for (int dg = 0; dg < 4; dg++)
                o[dg][qg] = __builtin_amdgcn_mfma_f32_16x16x32_bf16(va[dg], pb, o[dg][qg], 0, 0, 0);
        }
        __builtin_amdgcn_s_setprio(0);

        // my K-DMA for tile kt+1 retired before the barrier publishes it
        if (kt + 1 < nt) asm volatile("s_waitcnt vmcnt(0)" ::: "memory");
        __builtin_amdgcn_s_barrier();
    }
#undef STAGE_K

    // ---- combine k-halves over the (dead) smem: 2 x 64 lanes x 40 f32 ----
    float* cmb = (float*)smem;
    float* slab = cmb + (size_t)qw * 2560 + lane * 40;
    if (kw == 1) {
#pragma unroll
        for (int dg = 0; dg < 4; dg++)
#pragma unroll
            for (int qg = 0; qg < 2; qg++)
                *(f32x4_a*)&slab[(dg * 2 + qg) * 4] = o[dg][qg];
#pragma unroll
        for (int qg = 0; qg < 2; qg++)
            *(f32x4_a*)&slab[32 + qg * 4] = lsum[qg];
    }
    __syncthreads();
    if (kw == 0) {
#pragma unroll
        for (int dg = 0; dg < 4; dg++)
#pragma unroll
            for (int qg = 0; qg < 2; qg++) {
                f32x4_a p = *(const f32x4_a*)&slab[(dg * 2 + qg) * 4];
#pragma unroll
                for (int r = 0; r < 4; r++) o[dg][qg][r] += p[r];
            }
#pragma unroll
        for (int qg = 0; qg < 2; qg++) {
            f32x4_a p = *(const f32x4_a*)&slab[32 + qg * 4];
            lsum[qg][0] += p[0];
        }

        // epilogue: lane holds O^T[d=dg*16+fq*4+r][q=q0w+qg*16+fr]
        const int bb = bh >> 4, hh = bh & 15;
#pragma unroll
        for (int qg = 0; qg < 2; qg++) {
            const float inv = 1.f / lsum[qg][0];
            u16* orow = O + ((size_t)(bb * 2048 + q0w + qg * 16 + fr)) * 1024 + hh * 64 + fq * 4;
#pragma unroll
            for (int dg = 0; dg < 4; dg++) {
                ushort4 h;
                h.x = f2bf(o[dg][qg][0] * inv);
                h.y = f2bf(o[dg][qg][1] * inv);
                h.z = f2bf(o[dg][qg][2] * inv);
                h.w = f2bf(o[dg][qg][3] * inv);
                *(ushort4*)&orow[dg * 16] = h;
            }
        }
    }
}

// ---------------------------------------------------------------------------
extern "C" void kernel_launch(void* const* d_in, const int* in_sizes, int n_in,
                              void* d_out, int out_size, void* d_ws, size_t ws_size,
                              hipStream_t stream) {
    const float* x      = (const float*)d_in[0];
    const float* w_qkv  = (const float*)d_in[1];
    const float* b_qkv  = (const float*)d_in[2];
    const float* w_proj = (const float*)d_in[3];
    const float* b_proj = (const float*)d_in[4];
    float* out = (float*)d_out;

    u16* ws = (u16*)d_ws;
    u16* wqkvT  = ws;                      // 3072*1024
    u16* wprojT = wqkvT + 3072 * 1024;     // 1024*1024
    u16* Qb     = wprojT + 1024 * 1024;    // 32*2048*64
    u16* Kb     = Qb + 32 * 2048 * 64;
    u16* Vtb    = Kb + 32 * 2048 * 64;     // transposed V [BH,64,2048]
    u16* xb     = Vtb + 32 * 2048 * 64;    // x as bf16; reused as attnO
    u16* attnO  = xb;                      // alias (xb dead after gemm1)

    prep_kernel<<<6144, 256, 0, stream>>>(x, xb, w_qkv, wqkvT, w_proj, wprojT);

    gemm_m97<0, 128><<<dim3(24, 32), 256, 0, stream>>>(
        xb, wqkvT, b_qkv, nullptr, Qb, Kb, Vtb, 4096, 3072, 1024);

    attn_kernel<<<1024, 256, 0, stream>>>(Qb, Kb, Vtb, attnO);

    gemm_m97<1, 64><<<dim3(16, 32), 256, 0, stream>>>(
        attnO, wprojT, b_proj, out, nullptr, nullptr, nullptr, 4096, 1024, 1024);
}

// Round 14
// 97.181 us; speedup vs baseline: 1.1689x; 1.1689x over previous
//
#include <hip/hip_runtime.h>

typedef short bf16x8 __attribute__((ext_vector_type(8)));
typedef float f32x4 __attribute__((ext_vector_type(4)));
typedef unsigned short u16;
typedef unsigned short u16x8 __attribute__((ext_vector_type(8)));
typedef unsigned short u16x4 __attribute__((ext_vector_type(4), may_alias));
typedef float f32x4_a __attribute__((ext_vector_type(4), may_alias));

__device__ __forceinline__ u16 f2bf(float f) {
    union { float f; unsigned u; } v; v.f = f;
    unsigned r = v.u + 0x7fffu + ((v.u >> 16) & 1u);
    return (u16)(r >> 16);
}
// cheap round-half-up (for P: normalization cancels the tiny bias)
__device__ __forceinline__ u16 f2bf_rhu(float f) {
    union { float f; unsigned u; } v; v.f = f;
    return (u16)((v.u + 0x8000u) >> 16);
}

// async global->LDS, 16B per lane. lds base must be wave-uniform (HW adds lane*16).
__device__ __forceinline__ void gld_lds16(const void* g, void* l) {
    __builtin_amdgcn_global_load_lds(
        (const __attribute__((address_space(1))) void*)g,
        (__attribute__((address_space(3))) void*)l, 16, 0, 0);
}

// ---------------------------------------------------------------------------
// Fused prep: x fp32->bf16 (blocks 0..2047), w_qkv transpose+cvt (2048..5119),
// w_proj transpose+cvt (5120..6143).
// ---------------------------------------------------------------------------
__global__ __launch_bounds__(256) void prep_kernel(
    const float* __restrict__ x, u16* __restrict__ xb,
    const float* __restrict__ w_qkv, u16* __restrict__ wqkvT,
    const float* __restrict__ w_proj, u16* __restrict__ wprojT) {
    __shared__ float tile[32][33];
    const int b = blockIdx.x, tid = threadIdx.x;
    if (b < 2048) {
        const int i = b * 256 + tid;
        float4 a = ((const float4*)x)[i * 2];
        float4 c = ((const float4*)x)[i * 2 + 1];
        u16x8 h;
        h[0] = f2bf(a.x); h[1] = f2bf(a.y); h[2] = f2bf(a.z); h[3] = f2bf(a.w);
        h[4] = f2bf(c.x); h[5] = f2bf(c.y); h[6] = f2bf(c.z); h[7] = f2bf(c.w);
        *(u16x8*)(xb + (size_t)i * 8) = h;
        return;
    }
    const float* in; u16* out; int N, bx;
    if (b < 5120) { bx = b - 2048; in = w_qkv; out = wqkvT; N = 3072; }
    else          { bx = b - 5120; in = w_proj; out = wprojT; N = 1024; }
    const int nblk = N / 32;
    const int n0 = (bx % nblk) * 32, k0 = (bx / nblk) * 32;
    const int tx = tid & 31, ty = tid >> 5;
#pragma unroll
    for (int i = 0; i < 32; i += 8)
        tile[ty + i][tx] = in[(size_t)(k0 + ty + i) * N + n0 + tx];
    __syncthreads();
#pragma unroll
    for (int i = 0; i < 32; i += 8)
        out[(size_t)(n0 + ty + i) * 1024 + k0 + tx] = f2bf(tile[tx][ty + i]);
}

// ---------------------------------------------------------------------------
// GEMM: C[M,N] = A[M,K](bf16) * Bt[N,K]^T + bias
// BM=128, BN in {128,64}. 4 waves (2x2), BK=64, global_load_lds x16 staging
// with both-sides XOR swizzle (frag reads 2-way = free), 16 K-steps.
// OUTMODE 0: scatter Q (pre-scaled by 0.125*log2e) / K as [B,H,T,D],
//            V transposed as [B,H,D,T].  OUTMODE 1: fp32 C + bias.
// ---------------------------------------------------------------------------
#define QSCALE 0.180336880f  // 0.125 * log2(e)

template <int OUTMODE, int BN>
__global__ __launch_bounds__(256) void gemm_m97(
    const u16* __restrict__ A, const u16* __restrict__ Bt,
    const float* __restrict__ bias, float* __restrict__ Cf,
    u16* __restrict__ Qo, u16* __restrict__ Ko, u16* __restrict__ Vt,
    int M, int N, int K) {
    constexpr int NF = BN / 32;  // n-frags per wave (wave covers BN/2 cols)
    __shared__ __align__(16) u16 lA[128 * 64];
    __shared__ __align__(16) u16 lB[BN * 64];

    const int tid = threadIdx.x;
    const int lane = tid & 63, wid = tid >> 6;
    const int wr = wid >> 1, wc = wid & 1;
    const int fr = lane & 15, fq = lane >> 4;
    const int m0 = blockIdx.y * 128, n0 = blockIdx.x * BN;

    const int gsrc = (lane & 7) ^ (lane >> 3);
    const u16* gA0 = A + (size_t)(m0 + (tid >> 3)) * K + gsrc * 8;
    const u16* gB0 = Bt + (size_t)(n0 + (tid >> 3)) * K + gsrc * 8;
    u16* lAw = lA + wid * 512;
    u16* lBw = lB + wid * 512;

    const int r7 = fr & 7;
    const int gk[2] = { ((0 + fq) ^ r7) * 8, ((4 + fq) ^ r7) * 8 };

    f32x4 acc[4][NF];
#pragma unroll
    for (int m = 0; m < 4; m++)
#pragma unroll
        for (int n = 0; n < NF; n++)
#pragma unroll
            for (int r = 0; r < 4; r++) acc[m][n][r] = 0.f;

    for (int k0 = 0; k0 < K; k0 += 64) {
        __syncthreads();
#pragma unroll
        for (int c = 0; c < 4; c++)
            gld_lds16(gA0 + (size_t)(c * 32) * K + k0, lAw + c * 2048);
#pragma unroll
        for (int c = 0; c < BN / 32; c++)
            gld_lds16(gB0 + (size_t)(c * 32) * K + k0, lBw + c * 2048);
        __syncthreads();

#pragma unroll
        for (int kf = 0; kf < 2; kf++) {
            bf16x8 a[4], b[NF];
#pragma unroll
            for (int m = 0; m < 4; m++)
                a[m] = *(const bf16x8*)&lA[(wr * 64 + m * 16 + fr) * 64 + gk[kf]];
#pragma unroll
            for (int n = 0; n < NF; n++)
                b[n] = *(const bf16x8*)&lB[(wc * (BN / 2) + n * 16 + fr) * 64 + gk[kf]];
#pragma unroll
            for (int m = 0; m < 4; m++)
#pragma unroll
                for (int n = 0; n < NF; n++)
                    acc[m][n] = __builtin_amdgcn_mfma_f32_16x16x32_bf16(a[m], b[n], acc[m][n], 0, 0, 0);
        }
    }

#pragma unroll
    for (int m = 0; m < 4; m++) {
#pragma unroll
        for (int n = 0; n < NF; n++) {
            const int row0 = m0 + wr * 64 + m * 16 + fq * 4;
            const int col = n0 + wc * (BN / 2) + n * 16 + fr;
            float v4[4];
#pragma unroll
            for (int r = 0; r < 4; r++) v4[r] = acc[m][n][r] + bias[col];
            if (OUTMODE == 0) {
                const int bb = row0 >> 11, t0 = row0 & 2047;
                const int sec = col >> 10, cc = col & 1023;
                const int h = cc >> 6, d = cc & 63;
                if (sec == 0) {
#pragma unroll
                    for (int r = 0; r < 4; r++)
                        Qo[(((size_t)(bb * 16 + h) * 2048 + t0 + r) << 6) + d] = f2bf(v4[r] * QSCALE);
                } else if (sec == 1) {
#pragma unroll
                    for (int r = 0; r < 4; r++)
                        Ko[(((size_t)(bb * 16 + h) * 2048 + t0 + r) << 6) + d] = f2bf(v4[r]);
                } else {
                    ushort4 p;
                    p.x = f2bf(v4[0]); p.y = f2bf(v4[1]); p.z = f2bf(v4[2]); p.w = f2bf(v4[3]);
                    *(ushort4*)&Vt[(((size_t)(bb * 16 + h) * 64 + d) << 11) + t0] = p;
                }
            } else {
#pragma unroll
                for (int r = 0; r < 4; r++)
                    Cf[(size_t)(row0 + r) * N + col] = v4[r];
            }
        }
    }
}

// ---------------------------------------------------------------------------
// Causal flash attention, swapped-operand + 2x2 wave role split (R12 structure;
// R13's V-from-global was a regression: 16-line gathers beat LDS round-trip).
// NEW vs R12: lP granule swizzle uses r4x = (fr&3)^(fr>>2) instead of (ql&3).
// R13 counters isolated ~3.5M bank-conflict cycles to lP [32x32]: bank index
// depended on fr only via fr&3, so lanes fr,fr+4,fr+8,fr+12 4-way-conflicted
// on every lP access. XOR-ing with fr>>2 gives those lanes distinct banks;
// content mapping unchanged (same constant XOR on write and read cancels).
// Q,K bf16 [BH,T,64]; Vt bf16 [BH,64,T]; O bf16 [B,T,H*64].
// Block: 4 waves, 64 q-rows; grid 1024, heavy q-tiles first.
// ---------------------------------------------------------------------------
__global__ __launch_bounds__(256, 4) void attn_kernel(const u16* __restrict__ Q,
                                                      const u16* __restrict__ Kg,
                                                      const u16* __restrict__ Vt,
                                                      u16* __restrict__ O) {
    __shared__ __align__(16) u16 lK[2][64 * 64];  // double-buffered, swizzled
    __shared__ __align__(16) u16 lV[2][64 * 64];
    __shared__ __align__(16) u16 lP[4][32 * 32];  // per-wave P[q32][k32], swizzled

    const int tid = threadIdx.x;
    const int lane = tid & 63, wid = tid >> 6;
    const int fr = lane & 15, fq = lane >> 4;
    const int kw = wid >> 1, qw = wid & 1;  // k-half / q-half roles
    const int bh = blockIdx.x & 31;
    const int qi = 31 - (blockIdx.x >> 5);  // heavy blocks first
    const int qb0 = qi * 64;
    const size_t base = (size_t)bh * (2048 * 64);
    const u16* Qp = Q + base;
    const u16* Kp = Kg + base;
    const u16* Vp = Vt + base;  // [64][2048]

    const int q0w = qb0 + qw * 32;
    bf16x8 qa[2][2];  // [qg][kf]
#pragma unroll
    for (int qg = 0; qg < 2; qg++)
#pragma unroll
        for (int kf = 0; kf < 2; kf++)
            qa[qg][kf] = *(const bf16x8*)&Qp[(size_t)(q0w + qg * 16 + fr) * 64 + kf * 32 + fq * 8];
    asm volatile("s_waitcnt vmcnt(0)" ::: "memory");

    bf16x8 vones;
#pragma unroll
    for (int j = 0; j < 8; j++) vones[j] = (short)0x3F80;  // bf16 1.0

    f32x4 o[4][2], lsum[2];  // [dg][qg] / [qg]
#pragma unroll
    for (int qg = 0; qg < 2; qg++) {
#pragma unroll
        for (int r = 0; r < 4; r++) lsum[qg][r] = 0.f;
#pragma unroll
        for (int dg = 0; dg < 4; dg++)
#pragma unroll
            for (int r = 0; r < 4; r++) o[dg][qg][r] = 0.f;
    }

    // --- staging geometry (both-sides swizzle, rule #21) ---
    const int srow0 = wid * 8 + (lane >> 3);
    const int gsrc = (lane & 7) ^ (lane >> 3);
    const u16* kSrc0 = Kp + (size_t)srow0 * 64 + gsrc * 8;
    const u16* vSrc0 = Vp + ((size_t)srow0 << 11) + gsrc * 8;

    // --- fragment read granules (same XOR on read) ---
    const int r7 = fr & 7;
    const int gk0 = ((0 + fq) ^ r7) * 8;        // K d-granule, kf=0
    const int gk1 = ((4 + fq) ^ r7) * 8;        // K d-granule, kf=1
    const int gkv = ((kw * 4 + fq) ^ r7) * 8;   // V k-granule for this k-half

    // --- lP bank-spread constant (the R14 fix) ---
    const int r4x = (fr & 3) ^ (fr >> 2);

    const int nt = qi + 1;

#define STAGE(buf, kt0_)                                                        \
    do {                                                                        \
        const int _kt0 = (kt0_);                                                \
        u16* _lkw = &lK[buf][wid * 512];                                        \
        u16* _lvw = &lV[buf][wid * 512];                                        \
        gld_lds16(kSrc0 + (size_t)_kt0 * 64, _lkw);                             \
        gld_lds16(kSrc0 + (size_t)(_kt0 + 32) * 64, _lkw + 2048);               \
        gld_lds16(vSrc0 + _kt0, _lvw);                                          \
        gld_lds16(vSrc0 + ((size_t)32 << 11) + _kt0, _lvw + 2048);              \
    } while (0)

    STAGE(0, 0);  // prologue

    for (int kt = 0; kt < nt; kt++) {
        const int cur = kt & 1;
        if (kt + 1 < nt) {
            STAGE(cur ^ 1, (kt + 1) << 6);
            asm volatile("s_waitcnt vmcnt(4)" ::: "memory");  // tile kt landed
        } else {
            asm volatile("s_waitcnt vmcnt(0)" ::: "memory");
        }
        __builtin_amdgcn_s_barrier();

        const int kt0 = kt << 6;
        const u16* lKc = lK[cur];
        const u16* lVc = lV[cur];

        // S^T[k32][q32] = K_half Q_half^T   (exp2 domain; Q pre-scaled)
        f32x4 s[2][2];  // [kg][qg]
#pragma unroll
        for (int kg = 0; kg < 2; kg++)
#pragma unroll
            for (int qg = 0; qg < 2; qg++)
#pragma unroll
                for (int r = 0; r < 4; r++) s[kg][qg][r] = 0.f;
        __builtin_amdgcn_s_setprio(1);
#pragma unroll
        for (int kg = 0; kg < 2; kg++) {
            const int krow = (kw * 32 + kg * 16 + fr) * 64;
            bf16x8 kb0 = *(const bf16x8*)&lKc[krow + gk0];
            bf16x8 kb1 = *(const bf16x8*)&lKc[krow + gk1];
#pragma unroll
            for (int qg = 0; qg < 2; qg++) {
                s[kg][qg] = __builtin_amdgcn_mfma_f32_16x16x32_bf16(kb0, qa[qg][0], s[kg][qg], 0, 0, 0);
                s[kg][qg] = __builtin_amdgcn_mfma_f32_16x16x32_bf16(kb1, qa[qg][1], s[kg][qg], 0, 0, 0);
            }
        }
        __builtin_amdgcn_s_setprio(0);

        if (kt == nt - 1) {  // only the diagonal tile can cross the boundary
#pragma unroll
            for (int kg = 0; kg < 2; kg++) {
                const int kg0 = kt0 + kw * 32 + kg * 16 + fq * 4;
#pragma unroll
                for (int qg = 0; qg < 2; qg++) {
                    const int qg0 = q0w + qg * 16 + fr;
#pragma unroll
                    for (int r = 0; r < 4; r++)
                        if (kg0 + r > qg0) s[kg][qg][r] = -200.f;  // exp2 -> 0
                }
            }
        }

        // P = exp2(S) -> lP[q32][k32]: b64 at row q, granule (kg*2+(fq>>1))^r4x
#pragma unroll
        for (int kg = 0; kg < 2; kg++)
#pragma unroll
            for (int qg = 0; qg < 2; qg++) {
                const int ql = qg * 16 + fr;
                u16x4 w;
                w[0] = f2bf_rhu(__builtin_amdgcn_exp2f(s[kg][qg][0]));
                w[1] = f2bf_rhu(__builtin_amdgcn_exp2f(s[kg][qg][1]));
                w[2] = f2bf_rhu(__builtin_amdgcn_exp2f(s[kg][qg][2]));
                w[3] = f2bf_rhu(__builtin_amdgcn_exp2f(s[kg][qg][3]));
                const int g = (kg * 2 + (fq >> 1)) ^ r4x;
                *(u16x4*)&lP[wid][ql * 32 + g * 8 + (fq & 1) * 4] = w;
            }
        asm volatile("" ::: "memory");  // order lP writes before lP reads

        // O^T += V^T_half P ; l += 1*P   (per q-group)
        __builtin_amdgcn_s_setprio(1);
        bf16x8 va[4];
#pragma unroll
        for (int dg = 0; dg < 4; dg++)
            va[dg] = *(const bf16x8*)&lVc[(dg * 16 + fr) * 64 + gkv];
#pragma unroll
        for (int qg = 0; qg < 2; qg++) {
            const int ql = qg * 16 + fr;
            bf16x8 pb = *(const bf16x8*)&lP[wid][ql * 32 + (fq ^ r4x) * 8];
            lsum[qg] = __builtin_amdgcn_mfma_f32_16x16x32_bf16(vones, pb, lsum[qg], 0, 0, 0);
#pragma unroll
            for (int dg = 0; dg < 4; dg++)
                o[dg][qg] = __builtin_amdgcn_mfma_f32_16x16x32_bf16(va[dg], pb, o[dg][qg], 0, 0, 0);
        }
        __builtin_amdgcn_s_setprio(0);

        __builtin_amdgcn_s_barrier();  // buf[cur] free to overwrite next iter
    }
#undef STAGE

    // ---- combine k-halves: kw=1 writes partials into (dead) lK, kw=0 adds ----
    float* cmb = (float*)&lK[0][0];  // 2 slabs x 64 lanes x 40 f32 = 20 KB
    float* slab = cmb + (size_t)qw * 2560 + lane * 40;
    if (kw == 1) {
#pragma unroll
        for (int dg = 0; dg < 4; dg++)
#pragma unroll
            for (int qg = 0; qg < 2; qg++)
                *(f32x4_a*)&slab[(dg * 2 + qg) * 4] = o[dg][qg];
#pragma unroll
        for (int qg = 0; qg < 2; qg++)
            *(f32x4_a*)&slab[32 + qg * 4] = lsum[qg];
    }
    __syncthreads();
    if (kw == 0) {
#pragma unroll
        for (int dg = 0; dg < 4; dg++)
#pragma unroll
            for (int qg = 0; qg < 2; qg++) {
                f32x4_a p = *(const f32x4_a*)&slab[(dg * 2 + qg) * 4];
#pragma unroll
                for (int r = 0; r < 4; r++) o[dg][qg][r] += p[r];
            }
#pragma unroll
        for (int qg = 0; qg < 2; qg++) {
            f32x4_a p = *(const f32x4_a*)&slab[32 + qg * 4];
            lsum[qg][0] += p[0];
        }

        // epilogue: lane holds O^T[d=dg*16+fq*4+r][q=q0w+qg*16+fr]
        const int bb = bh >> 4, hh = bh & 15;
#pragma unroll
        for (int qg = 0; qg < 2; qg++) {
            const float inv = 1.f / lsum[qg][0];
            u16* orow = O + ((size_t)(bb * 2048 + q0w + qg * 16 + fr)) * 1024 + hh * 64 + fq * 4;
#pragma unroll
            for (int dg = 0; dg < 4; dg++) {
                ushort4 h;
                h.x = f2bf(o[dg][qg][0] * inv);
                h.y = f2bf(o[dg][qg][1] * inv);
                h.z = f2bf(o[dg][qg][2] * inv);
                h.w = f2bf(o[dg][qg][3] * inv);
                *(ushort4*)&orow[dg * 16] = h;
            }
        }
    }
}

// ---------------------------------------------------------------------------
extern "C" void kernel_launch(void* const* d_in, const int* in_sizes, int n_in,
                              void* d_out, int out_size, void* d_ws, size_t ws_size,
                              hipStream_t stream) {
    const float* x      = (const float*)d_in[0];
    const float* w_qkv  = (const float*)d_in[1];
    const float* b_qkv  = (const float*)d_in[2];
    const float* w_proj = (const float*)d_in[3];
    const float* b_proj = (const float*)d_in[4];
    float* out = (float*)d_out;

    u16* ws = (u16*)d_ws;
    u16* wqkvT  = ws;                      // 3072*1024
    u16* wprojT = wqkvT + 3072 * 1024;     // 1024*1024
    u16* Qb     = wprojT + 1024 * 1024;    // 32*2048*64
    u16* Kb     = Qb + 32 * 2048 * 64;
    u16* Vtb    = Kb + 32 * 2048 * 64;     // transposed V [BH,64,2048]
    u16* xb     = Vtb + 32 * 2048 * 64;    // x as bf16; reused as attnO
    u16* attnO  = xb;                      // alias (xb dead after gemm1)

    prep_kernel<<<6144, 256, 0, stream>>>(x, xb, w_qkv, wqkvT, w_proj, wprojT);

    gemm_m97<0, 128><<<dim3(24, 32), 256, 0, stream>>>(
        xb, wqkvT, b_qkv, nullptr, Qb, Kb, Vtb, 4096, 3072, 1024);

    attn_kernel<<<1024, 256, 0, stream>>>(Qb, Kb, Vtb, attnO);

    gemm_m97<1, 64><<<dim3(16, 32), 256, 0, stream>>>(
        attnO, wprojT, b_proj, out, nullptr, nullptr, nullptr, 4096, 1024, 1024);
}

// Round 16
// 97.046 us; speedup vs baseline: 1.1706x; 1.0014x over previous
//
#include <hip/hip_runtime.h>

typedef short bf16x8 __attribute__((ext_vector_type(8)));
typedef float f32x4 __attribute__((ext_vector_type(4)));
typedef unsigned short u16;
typedef unsigned short u16x8 __attribute__((ext_vector_type(8)));
typedef unsigned short u16x4 __attribute__((ext_vector_type(4), may_alias));
typedef float f32x4_a __attribute__((ext_vector_type(4), may_alias));

__device__ __forceinline__ u16 f2bf(float f) {
    union { float f; unsigned u; } v; v.f = f;
    unsigned r = v.u + 0x7fffu + ((v.u >> 16) & 1u);
    return (u16)(r >> 16);
}
// cheap round-half-up (for P: normalization cancels the tiny bias)
__device__ __forceinline__ u16 f2bf_rhu(float f) {
    union { float f; unsigned u; } v; v.f = f;
    return (u16)((v.u + 0x8000u) >> 16);
}

// async global->LDS, 16B per lane. lds base must be wave-uniform (HW adds lane*16).
__device__ __forceinline__ void gld_lds16(const void* g, void* l) {
    __builtin_amdgcn_global_load_lds(
        (const __attribute__((address_space(1))) void*)g,
        (__attribute__((address_space(3))) void*)l, 16, 0, 0);
}

// ---------------------------------------------------------------------------
// Fused prep: x fp32->bf16 (blocks 0..2047), w_qkv transpose+cvt (2048..5119),
// w_proj transpose+cvt (5120..6143).
// ---------------------------------------------------------------------------
__global__ __launch_bounds__(256) void prep_kernel(
    const float* __restrict__ x, u16* __restrict__ xb,
    const float* __restrict__ w_qkv, u16* __restrict__ wqkvT,
    const float* __restrict__ w_proj, u16* __restrict__ wprojT) {
    __shared__ float tile[32][33];
    const int b = blockIdx.x, tid = threadIdx.x;
    if (b < 2048) {
        const int i = b * 256 + tid;
        float4 a = ((const float4*)x)[i * 2];
        float4 c = ((const float4*)x)[i * 2 + 1];
        u16x8 h;
        h[0] = f2bf(a.x); h[1] = f2bf(a.y); h[2] = f2bf(a.z); h[3] = f2bf(a.w);
        h[4] = f2bf(c.x); h[5] = f2bf(c.y); h[6] = f2bf(c.z); h[7] = f2bf(c.w);
        *(u16x8*)(xb + (size_t)i * 8) = h;
        return;
    }
    const float* in; u16* out; int N, bx;
    if (b < 5120) { bx = b - 2048; in = w_qkv; out = wqkvT; N = 3072; }
    else          { bx = b - 5120; in = w_proj; out = wprojT; N = 1024; }
    const int nblk = N / 32;
    const int n0 = (bx % nblk) * 32, k0 = (bx / nblk) * 32;
    const int tx = tid & 31, ty = tid >> 5;
#pragma unroll
    for (int i = 0; i < 32; i += 8)
        tile[ty + i][tx] = in[(size_t)(k0 + ty + i) * N + n0 + tx];
    __syncthreads();
#pragma unroll
    for (int i = 0; i < 32; i += 8)
        out[(size_t)(n0 + ty + i) * 1024 + k0 + tx] = f2bf(tile[tx][ty + i]);
}

// ---------------------------------------------------------------------------
// GEMM: C[M,N] = A[M,K](bf16) * Bt[N,K]^T + bias
// BM=128, BN in {128,64}. 4 waves (2x2), BK=64, global_load_lds x16 staging
// with both-sides XOR swizzle (frag reads 2-way = free), 16 K-steps.
// OUTMODE 0: scatter Q (pre-scaled by 0.125*log2e) / K as [B,H,T,D],
//            V transposed as [B,H,D,T].  OUTMODE 1: fp32 C + bias.
// ---------------------------------------------------------------------------
#define QSCALE 0.180336880f  // 0.125 * log2(e)

template <int OUTMODE, int BN>
__global__ __launch_bounds__(256) void gemm_m97(
    const u16* __restrict__ A, const u16* __restrict__ Bt,
    const float* __restrict__ bias, float* __restrict__ Cf,
    u16* __restrict__ Qo, u16* __restrict__ Ko, u16* __restrict__ Vt,
    int M, int N, int K) {
    constexpr int NF = BN / 32;  // n-frags per wave (wave covers BN/2 cols)
    __shared__ __align__(16) u16 lA[128 * 64];
    __shared__ __align__(16) u16 lB[BN * 64];

    const int tid = threadIdx.x;
    const int lane = tid & 63, wid = tid >> 6;
    const int wr = wid >> 1, wc = wid & 1;
    const int fr = lane & 15, fq = lane >> 4;
    const int m0 = blockIdx.y * 128, n0 = blockIdx.x * BN;

    const int gsrc = (lane & 7) ^ (lane >> 3);
    const u16* gA0 = A + (size_t)(m0 + (tid >> 3)) * K + gsrc * 8;
    const u16* gB0 = Bt + (size_t)(n0 + (tid >> 3)) * K + gsrc * 8;
    u16* lAw = lA + wid * 512;
    u16* lBw = lB + wid * 512;

    const int r7 = fr & 7;
    const int gk[2] = { ((0 + fq) ^ r7) * 8, ((4 + fq) ^ r7) * 8 };

    f32x4 acc[4][NF];
#pragma unroll
    for (int m = 0; m < 4; m++)
#pragma unroll
        for (int n = 0; n < NF; n++)
#pragma unroll
            for (int r = 0; r < 4; r++) acc[m][n][r] = 0.f;

    for (int k0 = 0; k0 < K; k0 += 64) {
        __syncthreads();
#pragma unroll
        for (int c = 0; c < 4; c++)
            gld_lds16(gA0 + (size_t)(c * 32) * K + k0, lAw + c * 2048);
#pragma unroll
        for (int c = 0; c < BN / 32; c++)
            gld_lds16(gB0 + (size_t)(c * 32) * K + k0, lBw + c * 2048);
        __syncthreads();

#pragma unroll
        for (int kf = 0; kf < 2; kf++) {
            bf16x8 a[4], b[NF];
#pragma unroll
            for (int m = 0; m < 4; m++)
                a[m] = *(const bf16x8*)&lA[(wr * 64 + m * 16 + fr) * 64 + gk[kf]];
#pragma unroll
            for (int n = 0; n < NF; n++)
                b[n] = *(const bf16x8*)&lB[(wc * (BN / 2) + n * 16 + fr) * 64 + gk[kf]];
#pragma unroll
            for (int m = 0; m < 4; m++)
#pragma unroll
                for (int n = 0; n < NF; n++)
                    acc[m][n] = __builtin_amdgcn_mfma_f32_16x16x32_bf16(a[m], b[n], acc[m][n], 0, 0, 0);
        }
    }

#pragma unroll
    for (int m = 0; m < 4; m++) {
#pragma unroll
        for (int n = 0; n < NF; n++) {
            const int row0 = m0 + wr * 64 + m * 16 + fq * 4;
            const int col = n0 + wc * (BN / 2) + n * 16 + fr;
            float v4[4];
#pragma unroll
            for (int r = 0; r < 4; r++) v4[r] = acc[m][n][r] + bias[col];
            if (OUTMODE == 0) {
                const int bb = row0 >> 11, t0 = row0 & 2047;
                const int sec = col >> 10, cc = col & 1023;
                const int h = cc >> 6, d = cc & 63;
                if (sec == 0) {
#pragma unroll
                    for (int r = 0; r < 4; r++)
                        Qo[(((size_t)(bb * 16 + h) * 2048 + t0 + r) << 6) + d] = f2bf(v4[r] * QSCALE);
                } else if (sec == 1) {
#pragma unroll
                    for (int r = 0; r < 4; r++)
                        Ko[(((size_t)(bb * 16 + h) * 2048 + t0 + r) << 6) + d] = f2bf(v4[r]);
                } else {
                    ushort4 p;
                    p.x = f2bf(v4[0]); p.y = f2bf(v4[1]); p.z = f2bf(v4[2]); p.w = f2bf(v4[3]);
                    *(ushort4*)&Vt[(((size_t)(bb * 16 + h) * 64 + d) << 11) + t0] = p;
                }
            } else {
#pragma unroll
                for (int r = 0; r < 4; r++)
                    Cf[(size_t)(row0 + r) * N + col] = v4[r];
            }
        }
    }
}

// ---------------------------------------------------------------------------
// Causal flash attention (R14 structure) + single-buffered V -> 32 KB LDS,
// 5 blocks/CU. R15 NaN post-mortem fixes:
//  (1) last tile MUST drain its K/V DMAs: else-branch vmcnt(0)+barrier
//      (R15 read unlanded LDS on the final tile -> inf/NaN);
//  (2) __syncthreads() after the loop before the combine overlay writes
//      (kw=1 waves were overwriting lK/lV while slow waves still read them).
// vmcnt bookkeeping (per wave, in-order retirement): entering iter kt the
// wave has {K(kt):2, V(kt):2} in flight; issue K(kt+1), then vmcnt(2) retires
// exactly the 4 older ops, leaving K(kt+1) in flight. Prologue/tail drain 0.
// Q,K bf16 [BH,T,64]; Vt bf16 [BH,64,T]; O bf16 [B,T,H*64].
// Block: 4 waves (2x2 k-half x q-half roles), 64 q-rows; grid 1024 heavy-first.
// ---------------------------------------------------------------------------
__global__ __launch_bounds__(256, 4) void attn_kernel(const u16* __restrict__ Q,
                                                      const u16* __restrict__ Kg,
                                                      const u16* __restrict__ Vt,
                                                      u16* __restrict__ O) {
    // unified 32 KB: lK dbuf [2][64*64] + lV [64*64] + lP [4][32*32];
    // f32 combine scratch (20 KB) overlays the whole block after the loop.
    __shared__ __align__(16) u16 smem[16384];
    u16* lV = smem + 8192;
    u16* lPw;

    const int tid = threadIdx.x;
    const int lane = tid & 63, wid = tid >> 6;
    const int fr = lane & 15, fq = lane >> 4;
    const int kw = wid >> 1, qw = wid & 1;  // k-half / q-half roles
    lPw = smem + 12288 + wid * 1024;
    const int bh = blockIdx.x & 31;
    const int qi = 31 - (blockIdx.x >> 5);  // heavy blocks first
    const int qb0 = qi * 64;
    const size_t base = (size_t)bh * (2048 * 64);
    const u16* Qp = Q + base;
    const u16* Kp = Kg + base;
    const u16* Vp = Vt + base;  // [64][2048]

    const int q0w = qb0 + qw * 32;
    bf16x8 qa[2][2];  // [qg][kf]
#pragma unroll
    for (int qg = 0; qg < 2; qg++)
#pragma unroll
        for (int kf = 0; kf < 2; kf++)
            qa[qg][kf] = *(const bf16x8*)&Qp[(size_t)(q0w + qg * 16 + fr) * 64 + kf * 32 + fq * 8];
    // (qa loads drain at the prologue vmcnt(0) below)

    bf16x8 vones;
#pragma unroll
    for (int j = 0; j < 8; j++) vones[j] = (short)0x3F80;  // bf16 1.0

    f32x4 o[4][2], lsum[2];  // [dg][qg] / [qg]
#pragma unroll
    for (int qg = 0; qg < 2; qg++) {
#pragma unroll
        for (int r = 0; r < 4; r++) lsum[qg][r] = 0.f;
#pragma unroll
        for (int dg = 0; dg < 4; dg++)
#pragma unroll
            for (int r = 0; r < 4; r++) o[dg][qg][r] = 0.f;
    }

    // --- staging geometry (both-sides swizzle, rule #21) ---
    const int srow0 = wid * 8 + (lane >> 3);
    const int gsrc = (lane & 7) ^ (lane >> 3);
    const u16* kSrc0 = Kp + (size_t)srow0 * 64 + gsrc * 8;
    const u16* vSrc0 = Vp + ((size_t)srow0 << 11) + gsrc * 8;

    // --- fragment read granules (same XOR on read) ---
    const int r7 = fr & 7;
    const int gk0 = ((0 + fq) ^ r7) * 8;        // K d-granule, kf=0
    const int gk1 = ((4 + fq) ^ r7) * 8;        // K d-granule, kf=1
    const int gkv = ((kw * 4 + fq) ^ r7) * 8;   // V k-granule for this k-half

    // --- lP bank-spread constant (R14 fix) ---
    const int r4x = (fr & 3) ^ (fr >> 2);

    const int nt = qi + 1;

#define STAGE_K(bufofs, kt0_)                                                   \
    do {                                                                        \
        u16* _lkw = smem + (bufofs) + wid * 512;                                \
        gld_lds16(kSrc0 + (size_t)(kt0_) * 64, _lkw);                           \
        gld_lds16(kSrc0 + (size_t)((kt0_) + 32) * 64, _lkw + 2048);             \
    } while (0)
#define STAGE_V(kt0_)                                                           \
    do {                                                                        \
        u16* _lvw = lV + wid * 512;                                             \
        gld_lds16(vSrc0 + (kt0_), _lvw);                                        \
        gld_lds16(vSrc0 + ((size_t)32 << 11) + (kt0_), _lvw + 2048);            \
    } while (0)

    // prologue: K(0)+V(0), drain all (incl. qa), publish
    STAGE_K(0, 0);
    STAGE_V(0);
    asm volatile("s_waitcnt vmcnt(0)" ::: "memory");
    __builtin_amdgcn_s_barrier();

    for (int kt = 0; kt < nt; kt++) {
        const int kt0 = kt << 6;
        const int curofs = (kt & 1) ? 4096 : 0;

        if (kt + 1 < nt) {
            STAGE_K(curofs ^ 4096, kt0 + 64);
            asm volatile("s_waitcnt vmcnt(2)" ::: "memory");  // K(kt),V(kt) landed
            __builtin_amdgcn_s_barrier();
        } else if (nt > 1) {
            // last tile: K(nt-1),V(nt-1) still in flight from iter nt-2 (R15 bug #1)
            asm volatile("s_waitcnt vmcnt(0)" ::: "memory");
            __builtin_amdgcn_s_barrier();
        }
        // (nt==1: prologue already drained + synced)
        const u16* lKc = smem + curofs;

        // S^T[k32][q32] = K_half Q_half^T   (exp2 domain; Q pre-scaled)
        f32x4 s[2][2];  // [kg][qg]
#pragma unroll
        for (int kg = 0; kg < 2; kg++)
#pragma unroll
            for (int qg = 0; qg < 2; qg++)
#pragma unroll
                for (int r = 0; r < 4; r++) s[kg][qg][r] = 0.f;
        __builtin_amdgcn_s_setprio(1);
#pragma unroll
        for (int kg = 0; kg < 2; kg++) {
            const int krow = (kw * 32 + kg * 16 + fr) * 64;
            bf16x8 kb0 = *(const bf16x8*)&lKc[krow + gk0];
            bf16x8 kb1 = *(const bf16x8*)&lKc[krow + gk1];
#pragma unroll
            for (int qg = 0; qg < 2; qg++) {
                s[kg][qg] = __builtin_amdgcn_mfma_f32_16x16x32_bf16(kb0, qa[qg][0], s[kg][qg], 0, 0, 0);
                s[kg][qg] = __builtin_amdgcn_mfma_f32_16x16x32_bf16(kb1, qa[qg][1], s[kg][qg], 0, 0, 0);
            }
        }
        __builtin_amdgcn_s_setprio(0);

        if (kt == nt - 1) {  // only the diagonal tile can cross the boundary
#pragma unroll
            for (int kg = 0; kg < 2; kg++) {
                const int kg0 = kt0 + kw * 32 + kg * 16 + fq * 4;
#pragma unroll
                for (int qg = 0; qg < 2; qg++) {
                    const int qg0 = q0w + qg * 16 + fr;
#pragma unroll
                    for (int r = 0; r < 4; r++)
                        if (kg0 + r > qg0) s[kg][qg][r] = -200.f;  // exp2 -> 0
                }
            }
        }

        // P = exp2(S) -> lP[q32][k32]: b64 at row q, granule (kg*2+(fq>>1))^r4x
#pragma unroll
        for (int kg = 0; kg < 2; kg++)
#pragma unroll
            for (int qg = 0; qg < 2; qg++) {
                const int ql = qg * 16 + fr;
                u16x4 w;
                w[0] = f2bf_rhu(__builtin_amdgcn_exp2f(s[kg][qg][0]));
                w[1] = f2bf_rhu(__builtin_amdgcn_exp2f(s[kg][qg][1]));
                w[2] = f2bf_rhu(__builtin_amdgcn_exp2f(s[kg][qg][2]));
                w[3] = f2bf_rhu(__builtin_amdgcn_exp2f(s[kg][qg][3]));
                const int g = (kg * 2 + (fq >> 1)) ^ r4x;
                *(u16x4*)&lPw[ql * 32 + g * 8 + (fq & 1) * 4] = w;
            }
        asm volatile("" ::: "memory");  // order lP writes before lP reads

        // O^T += V^T_half P ; l += 1*P   (per q-group)
        __builtin_amdgcn_s_setprio(1);
        bf16x8 va[4];
#pragma unroll
        for (int dg = 0; dg < 4; dg++)
            va[dg] = *(const bf16x8*)&lV[(dg * 16 + fr) * 64 + gkv];
#pragma unroll
        for (int qg = 0; qg < 2; qg++) {
            const int ql = qg * 16 + fr;
            bf16x8 pb = *(const bf16x8*)&lPw[ql * 32 + (fq ^ r4x) * 8];
            lsum[qg] = __builtin_amdgcn_mfma_f32_16x16x32_bf16(vones, pb, lsum[qg], 0, 0, 0);
#pragma unroll
            for (int dg = 0; dg < 4; dg++)
                o[dg][qg] = __builtin_amdgcn_mfma_f32_16x16x32_bf16(va[dg], pb, o[dg][qg], 0, 0, 0);
        }
        __builtin_amdgcn_s_setprio(0);

        if (kt + 1 < nt) {
            __builtin_amdgcn_s_barrier();  // all waves done reading lV / lK[cur]
            STAGE_V(kt0 + 64);             // safe to overwrite lV now
        }
    }
#undef STAGE_K
#undef STAGE_V

    // all waves done with lK/lV before the overlay writes (R15 bug #2)
    __syncthreads();

    // ---- combine k-halves over the (dead) smem: 2 x 64 lanes x 40 f32 ----
    float* cmb = (float*)smem;
    float* slab = cmb + (size_t)qw * 2560 + lane * 40;
    if (kw == 1) {
#pragma unroll
        for (int dg = 0; dg < 4; dg++)
#pragma unroll
            for (int qg = 0; qg < 2; qg++)
                *(f32x4_a*)&slab[(dg * 2 + qg) * 4] = o[dg][qg];
#pragma unroll
        for (int qg = 0; qg < 2; qg++)
            *(f32x4_a*)&slab[32 + qg * 4] = lsum[qg];
    }
    __syncthreads();
    if (kw == 0) {
#pragma unroll
        for (int dg = 0; dg < 4; dg++)
#pragma unroll
            for (int qg = 0; qg < 2; qg++) {
                f32x4_a p = *(const f32x4_a*)&slab[(dg * 2 + qg) * 4];
#pragma unroll
                for (int r = 0; r < 4; r++) o[dg][qg][r] += p[r];
            }
#pragma unroll
        for (int qg = 0; qg < 2; qg++) {
            f32x4_a p = *(const f32x4_a*)&slab[32 + qg * 4];
            lsum[qg][0] += p[0];
        }

        // epilogue: lane holds O^T[d=dg*16+fq*4+r][q=q0w+qg*16+fr]
        const int bb = bh >> 4, hh = bh & 15;
#pragma unroll
        for (int qg = 0; qg < 2; qg++) {
            const float inv = 1.f / lsum[qg][0];
            u16* orow = O + ((size_t)(bb * 2048 + q0w + qg * 16 + fr)) * 1024 + hh * 64 + fq * 4;
#pragma unroll
            for (int dg = 0; dg < 4; dg++) {
                ushort4 h;
                h.x = f2bf(o[dg][qg][0] * inv);
                h.y = f2bf(o[dg][qg][1] * inv);
                h.z = f2bf(o[dg][qg][2] * inv);
                h.w = f2bf(o[dg][qg][3] * inv);
                *(ushort4*)&orow[dg * 16] = h;
            }
        }
    }
}

// ---------------------------------------------------------------------------
extern "C" void kernel_launch(void* const* d_in, const int* in_sizes, int n_in,
                              void* d_out, int out_size, void* d_ws, size_t ws_size,
                              hipStream_t stream) {
    const float* x      = (const float*)d_in[0];
    const float* w_qkv  = (const float*)d_in[1];
    const float* b_qkv  = (const float*)d_in[2];
    const float* w_proj = (const float*)d_in[3];
    const float* b_proj = (const float*)d_in[4];
    float* out = (float*)d_out;

    u16* ws = (u16*)d_ws;
    u16* wqkvT  = ws;                      // 3072*1024
    u16* wprojT = wqkvT + 3072 * 1024;     // 1024*1024
    u16* Qb     = wprojT + 1024 * 1024;    // 32*2048*64
    u16* Kb     = Qb + 32 * 2048 * 64;
    u16* Vtb    = Kb + 32 * 2048 * 64;     // transposed V [BH,64,2048]
    u16* xb     = Vtb + 32 * 2048 * 64;    // x as bf16; reused as attnO
    u16* attnO  = xb;                      // alias (xb dead after gemm1)

    prep_kernel<<<6144, 256, 0, stream>>>(x, xb, w_qkv, wqkvT, w_proj, wprojT);

    gemm_m97<0, 128><<<dim3(24, 32), 256, 0, stream>>>(
        xb, wqkvT, b_qkv, nullptr, Qb, Kb, Vtb, 4096, 3072, 1024);

    attn_kernel<<<1024, 256, 0, stream>>>(Qb, Kb, Vtb, attnO);

    gemm_m97<1, 64><<<dim3(16, 32), 256, 0, stream>>>(
        attnO, wprojT, b_proj, out, nullptr, nullptr, nullptr, 4096, 1024, 1024);
}